// Round 2
// baseline (64.034 us; speedup 1.0000x reference)
//
#include <hip/hip_runtime.h>
#include <hip/hip_bf16.h>

#define N_CELLS 776
#define N_ANCHORS 3
#define N_CH 7
#define CONF_THRESH 0.8f
#define NO_OBJECT 0.5f

#define CELLS_PER_BLOCK 64
#define N_BLOCKS ((N_CELLS + CELLS_PER_BLOCK - 1) / CELLS_PER_BLOCK)  // 13
#define DWORDS_PER_BLOCK (CELLS_PER_BLOCK * N_ANCHORS * N_CH)         // 1344

// Stage 1: 13 blocks x 64 threads (one wave per block). Coalesced staging of
// each block's 64 cells (64*21 dwords) into LDS, then one cell per lane,
// wave shuffle-reduce, one partial per block into d_ws.
__global__ __launch_bounds__(64) void yolo_partial_kernel(
    const float* __restrict__ pred,   // (N_CELLS*N_ANCHORS, N_CH) row-major
    const float* __restrict__ label,  // (N_CH,)
    float* __restrict__ partials)     // (N_BLOCKS,) in d_ws
{
    const int lane = threadIdx.x;           // 0..63
    const int blk  = blockIdx.x;            // 0..12

    const float l0 = label[0], l1 = label[1], l2 = label[2], l3 = label[3];
    const float l4 = label[4], l5 = label[5], l6 = label[6];

    // Coalesced global -> LDS staging: 21 fully-coalesced dword loads/lane.
    __shared__ float s[DWORDS_PER_BLOCK];
    const int gbase = blk * DWORDS_PER_BLOCK;
    #pragma unroll
    for (int k = 0; k < 21; ++k) {
        const int idx = k * 64 + lane;
        const int g = gbase + idx;
        if (g < N_CELLS * N_ANCHORS * N_CH) s[idx] = pred[g];
    }
    __syncthreads();  // single wave: near-free, orders LDS write->read

    const int cell = blk * CELLS_PER_BLOCK + lane;
    float loss = 0.0f;
    if (cell < N_CELLS) {
        // LDS reads: stride 21 dwords (odd) -> 2-way bank aliasing, free.
        const float* row = &s[lane * (N_ANCHORS * N_CH)];

        // argmax over anchors, first-occurrence tie semantics (strict '>').
        float best_iou = -INFINITY;
        float b[N_CH];
        #pragma unroll
        for (int a = 0; a < N_ANCHORS; ++a) {
            const float* p = row + a * N_CH;
            const float px = p[0], py = p[1], pw = p[2], ph = p[3];
            const float ax = fmaxf(px - pw * 0.5f, l0 - l2 * 0.5f);
            const float ay = fmaxf(py - ph * 0.5f, l1 - l3 * 0.5f);
            const float bx = fminf(px + pw * 0.5f, l0 + l2 * 0.5f);
            const float by = fminf(py + ph * 0.5f, l1 + l3 * 0.5f);
            const float inter = fabsf(fmaxf(bx - ax, 0.0f) * fmaxf(by - ay, 0.0f));
            const float area_a = fabsf(pw * ph);
            const float area_b = fabsf(l2 * l3);
            const float iou = inter / (area_a + area_b - inter);
            if (iou > best_iou) {
                best_iou = iou;
                #pragma unroll
                for (int c = 0; c < N_CH; ++c) b[c] = p[c];
            }
        }

        // Loss, replicating the reference exactly (wh_loss reuses label[0]/[1]
        // and best[:,0]/[:,1] — reference's own behavior, keep it).
        const float dx = l0 - b[0];
        const float dy = l1 - b[1];
        const float xy_loss = dx * dx + dy * dy;
        const float sw0 = sqrtf(l0) - sqrtf(b[0]);
        const float sw1 = sqrtf(l1) - sqrtf(b[1]);
        const float wh_loss = sw0 * sw0 + sw1 * sw1;
        const float coord_loss = xy_loss + wh_loss;

        const bool has_obj = b[4] > CONF_THRESH;
        const float d5 = l5 - b[5];
        const float d6 = l6 - b[6];
        const float class_loss = has_obj ? (d5 * d5 + d6 * d6) : 0.0f;
        const float d4 = l4 - b[4];
        const float conf_sq = d4 * d4;
        const float conf_loss = has_obj ? conf_sq : NO_OBJECT * conf_sq;

        loss = coord_loss + class_loss + conf_loss;
    }

    // Wave64 shuffle reduction; lane 0 stores the block partial.
    #pragma unroll
    for (int off = 32; off > 0; off >>= 1)
        loss += __shfl_down(loss, off, 64);
    if (lane == 0) partials[blk] = loss;
}

// Stage 2: one wave sums the 13 partials (deterministic, no atomics, no
// reliance on d_out/d_ws poison state).
__global__ __launch_bounds__(64) void yolo_final_kernel(
    const float* __restrict__ partials,
    float* __restrict__ out)
{
    const int lane = threadIdx.x;
    float v = (lane < N_BLOCKS) ? partials[lane] : 0.0f;
    #pragma unroll
    for (int off = 32; off > 0; off >>= 1)
        v += __shfl_down(v, off, 64);
    if (lane == 0) out[0] = v;
}

extern "C" void kernel_launch(void* const* d_in, const int* in_sizes, int n_in,
                              void* d_out, int out_size, void* d_ws, size_t ws_size,
                              hipStream_t stream) {
    const float* pred  = (const float*)d_in[0];   // (2328, 7) fp32
    const float* label = (const float*)d_in[1];   // (7,) fp32
    float* out = (float*)d_out;                   // scalar fp32
    float* partials = (float*)d_ws;               // 13 floats of scratch

    yolo_partial_kernel<<<N_BLOCKS, CELLS_PER_BLOCK, 0, stream>>>(pred, label, partials);
    yolo_final_kernel<<<1, 64, 0, stream>>>(partials, out);
}

// Round 3
// 61.497 us; speedup vs baseline: 1.0413x; 1.0413x over previous
//
#include <hip/hip_runtime.h>
#include <hip/hip_bf16.h>

#define N_CELLS 776
#define N_ANCHORS 3
#define N_CH 7
#define CONF_THRESH 0.8f
#define NO_OBJECT 0.5f

#define CELLS_PER_BLOCK 64
#define N_BLOCKS ((N_CELLS + CELLS_PER_BLOCK - 1) / CELLS_PER_BLOCK)  // 13
#define DWORDS_PER_BLOCK (CELLS_PER_BLOCK * N_ANCHORS * N_CH)         // 1344
#define SENTINEL 0x13579BDFu   // != 0xAAAAAAAA poison

// Single dispatch, 13 blocks x 64 lanes. Each block computes a 64-cell
// partial sum; block 0 collects via device-scope atomics (no second launch:
// each extra dispatch measured ~+7.4 us of graph-replay overhead in R2).
// Safe without cooperative launch: 13 blocks << 256 CUs -> all co-resident;
// flags/partials go through device-scope atomics so no XCD-coherence hazard;
// d_ws is re-poisoned to 0xAA each launch so SENTINEL is never stale-true.
__global__ __launch_bounds__(64) void yolo_loss_onepass(
    const float* __restrict__ pred,   // (N_CELLS*N_ANCHORS, N_CH) row-major
    const float* __restrict__ label,  // (N_CH,)
    float* __restrict__ out,          // scalar
    float* __restrict__ partials,     // d_ws[0..15]
    unsigned int* __restrict__ flags) // d_ws[16..31] (as uint)
{
    const int lane = threadIdx.x;           // 0..63
    const int blk  = blockIdx.x;            // 0..12

    const float l0 = label[0], l1 = label[1], l2 = label[2], l3 = label[3];
    const float l4 = label[4], l5 = label[5], l6 = label[6];

    // Coalesced global -> LDS staging: 21 coalesced dword loads/lane.
    __shared__ float s[DWORDS_PER_BLOCK];
    const int gbase = blk * DWORDS_PER_BLOCK;
    #pragma unroll
    for (int k = 0; k < 21; ++k) {
        const int idx = k * 64 + lane;
        const int g = gbase + idx;
        if (g < N_CELLS * N_ANCHORS * N_CH) s[idx] = pred[g];
    }
    __syncthreads();  // single wave: cheap; orders LDS write->read

    const int cell = blk * CELLS_PER_BLOCK + lane;
    float loss = 0.0f;
    if (cell < N_CELLS) {
        // LDS stride 21 dwords (odd) -> at most 2-way bank aliasing (free).
        const float* row = &s[lane * (N_ANCHORS * N_CH)];

        // argmax over anchors, first-occurrence ties (strict '>', a=0..2).
        float best_iou = -INFINITY;
        float b[N_CH];
        #pragma unroll
        for (int a = 0; a < N_ANCHORS; ++a) {
            const float* p = row + a * N_CH;
            const float px = p[0], py = p[1], pw = p[2], ph = p[3];
            const float ax = fmaxf(px - pw * 0.5f, l0 - l2 * 0.5f);
            const float ay = fmaxf(py - ph * 0.5f, l1 - l3 * 0.5f);
            const float bx = fminf(px + pw * 0.5f, l0 + l2 * 0.5f);
            const float by = fminf(py + ph * 0.5f, l1 + l3 * 0.5f);
            const float inter = fabsf(fmaxf(bx - ax, 0.0f) * fmaxf(by - ay, 0.0f));
            const float area_a = fabsf(pw * ph);
            const float area_b = fabsf(l2 * l3);
            const float iou = inter / (area_a + area_b - inter);
            if (iou > best_iou) {
                best_iou = iou;
                #pragma unroll
                for (int c = 0; c < N_CH; ++c) b[c] = p[c];
            }
        }

        // Loss exactly per reference (wh_loss reuses label[0]/[1] and
        // best[:,0]/[:,1] — reference's own quirk, preserved).
        const float dx = l0 - b[0];
        const float dy = l1 - b[1];
        const float xy_loss = dx * dx + dy * dy;
        const float sw0 = sqrtf(l0) - sqrtf(b[0]);
        const float sw1 = sqrtf(l1) - sqrtf(b[1]);
        const float wh_loss = sw0 * sw0 + sw1 * sw1;
        const float coord_loss = xy_loss + wh_loss;

        const bool has_obj = b[4] > CONF_THRESH;
        const float d5 = l5 - b[5];
        const float d6 = l6 - b[6];
        const float class_loss = has_obj ? (d5 * d5 + d6 * d6) : 0.0f;
        const float d4 = l4 - b[4];
        const float conf_sq = d4 * d4;
        const float conf_loss = has_obj ? conf_sq : NO_OBJECT * conf_sq;

        loss = coord_loss + class_loss + conf_loss;
    }

    // Wave64 shuffle reduction -> block partial in lane 0.
    #pragma unroll
    for (int off = 32; off > 0; off >>= 1)
        loss += __shfl_down(loss, off, 64);

    if (lane == 0) {
        atomicExch(&partials[blk], loss);     // device-scope store
        __threadfence();                      // release: partial before flag
        atomicExch(&flags[blk], SENTINEL);    // publish
    }

    // Block 0 collects: lane i polls flag i, atomically reads partial i,
    // wave-reduces the 13 partials, stores the scalar.
    if (blk == 0) {
        float v = 0.0f;
        if (lane < N_BLOCKS) {
            while (atomicCAS(&flags[lane], SENTINEL, SENTINEL) != SENTINEL) { }
            __threadfence();                  // acquire
            v = atomicAdd(&partials[lane], 0.0f);  // device-scope read
        }
        #pragma unroll
        for (int off = 32; off > 0; off >>= 1)
            v += __shfl_down(v, off, 64);
        if (lane == 0) out[0] = v;
    }
}

extern "C" void kernel_launch(void* const* d_in, const int* in_sizes, int n_in,
                              void* d_out, int out_size, void* d_ws, size_t ws_size,
                              hipStream_t stream) {
    const float* pred  = (const float*)d_in[0];   // (2328, 7) fp32
    const float* label = (const float*)d_in[1];   // (7,) fp32
    float* out = (float*)d_out;                   // scalar fp32
    float* partials = (float*)d_ws;               // 16 floats
    unsigned int* flags = (unsigned int*)d_ws + 16;

    yolo_loss_onepass<<<N_BLOCKS, CELLS_PER_BLOCK, 0, stream>>>(
        pred, label, out, partials, flags);
}

// Round 4
// 57.020 us; speedup vs baseline: 1.1230x; 1.0785x over previous
//
#include <hip/hip_runtime.h>
#include <hip/hip_bf16.h>

#define N_CELLS 776
#define N_ANCHORS 3
#define N_CH 7
#define CONF_THRESH 0.8f
#define NO_OBJECT 0.5f

#define TOTAL_DWORDS (N_CELLS * N_ANCHORS * N_CH)   // 16296 (= 4074 * 4)
#define TOTAL_FLOAT4 (TOTAL_DWORDS / 4)             // 4074

// Single dispatch, single block (R3 showed: +1 dispatch = +7.4us, atomic
// handshake = +5us — both losers; one block with no cross-block traffic is
// the floor structure). vs R1: replace 21 scalar stride-21 global loads per
// thread (latency/sectorization-bound on one CU) with fully-coalesced
// float4 staging into LDS, then compute from LDS (stride-21 dwords is odd
// -> 2-way bank aliasing, free).
__global__ __launch_bounds__(1024) void yolo_loss_kernel(
    const float* __restrict__ pred,   // (N_CELLS*N_ANCHORS, N_CH) row-major
    const float* __restrict__ label,  // (N_CH,)
    float* __restrict__ out)          // scalar
{
    const int tid = threadIdx.x;

    __shared__ float s[TOTAL_DWORDS];   // 65184 B of 160 KiB LDS

    // Coalesced float4 staging: 4 rounds x 1024 lanes (16B/lane).
    const float4* __restrict__ pred4 = (const float4*)pred;
    float4* s4 = (float4*)s;
    #pragma unroll
    for (int r = 0; r < 4; ++r) {
        const int idx = r * 1024 + tid;
        if (idx < TOTAL_FLOAT4) s4[idx] = pred4[idx];
    }

    // Uniform label loads (scalar path).
    const float l0 = label[0], l1 = label[1], l2 = label[2], l3 = label[3];
    const float l4 = label[4], l5 = label[5], l6 = label[6];

    __syncthreads();

    float loss = 0.0f;
    if (tid < N_CELLS) {
        const float* row = &s[tid * (N_ANCHORS * N_CH)];

        // argmax over anchors, first-occurrence ties (strict '>', a=0..2).
        float best_iou = -INFINITY;
        float b[N_CH];
        #pragma unroll
        for (int a = 0; a < N_ANCHORS; ++a) {
            const float* p = row + a * N_CH;
            const float px = p[0], py = p[1], pw = p[2], ph = p[3];
            const float ax = fmaxf(px - pw * 0.5f, l0 - l2 * 0.5f);
            const float ay = fmaxf(py - ph * 0.5f, l1 - l3 * 0.5f);
            const float bx = fminf(px + pw * 0.5f, l0 + l2 * 0.5f);
            const float by = fminf(py + ph * 0.5f, l1 + l3 * 0.5f);
            const float inter = fabsf(fmaxf(bx - ax, 0.0f) * fmaxf(by - ay, 0.0f));
            const float area_a = fabsf(pw * ph);
            const float area_b = fabsf(l2 * l3);
            const float iou = inter / (area_a + area_b - inter);
            if (iou > best_iou) {
                best_iou = iou;
                #pragma unroll
                for (int c = 0; c < N_CH; ++c) b[c] = p[c];
            }
        }

        // Loss exactly per reference (wh_loss reuses label[0]/[1] and
        // best[:,0]/[:,1] — the reference's own quirk, preserved).
        const float dx = l0 - b[0];
        const float dy = l1 - b[1];
        const float xy_loss = dx * dx + dy * dy;
        const float sw0 = sqrtf(l0) - sqrtf(b[0]);
        const float sw1 = sqrtf(l1) - sqrtf(b[1]);
        const float wh_loss = sw0 * sw0 + sw1 * sw1;
        const float coord_loss = xy_loss + wh_loss;

        const bool has_obj = b[4] > CONF_THRESH;
        const float d5 = l5 - b[5];
        const float d6 = l6 - b[6];
        const float class_loss = has_obj ? (d5 * d5 + d6 * d6) : 0.0f;
        const float d4 = l4 - b[4];
        const float conf_sq = d4 * d4;
        const float conf_loss = has_obj ? conf_sq : NO_OBJECT * conf_sq;

        loss = coord_loss + class_loss + conf_loss;
    }

    // Wave64 shuffle reduction, then LDS across the 16 waves.
    #pragma unroll
    for (int off = 32; off > 0; off >>= 1)
        loss += __shfl_down(loss, off, 64);

    __shared__ float warp_sums[16];
    const int wave = tid >> 6;
    if ((tid & 63) == 0) warp_sums[wave] = loss;
    __syncthreads();

    if (tid == 0) {
        float tot = 0.0f;
        #pragma unroll
        for (int w = 0; w < 16; ++w) tot += warp_sums[w];
        out[0] = tot;
    }
}

extern "C" void kernel_launch(void* const* d_in, const int* in_sizes, int n_in,
                              void* d_out, int out_size, void* d_ws, size_t ws_size,
                              hipStream_t stream) {
    const float* pred  = (const float*)d_in[0];   // (2328, 7) fp32
    const float* label = (const float*)d_in[1];   // (7,) fp32
    float* out = (float*)d_out;                   // scalar fp32
    yolo_loss_kernel<<<1, 1024, 0, stream>>>(pred, label, out);
}